// Round 12
// baseline (297.441 us; speedup 1.0000x reference)
//
#include <hip/hip_runtime.h>
#include <math.h>

// GAU attention: LN -> silu(x@W^T+b) x4 -> P=relu^2(QK^T/sqrt(T)) -> AV=P@V -> (U*AV)@Wo^T+bo
// R12: R11 (kf-major packed register streaming, 2x2 waves, ni-outer, XCD remap) +
// deeper A-pipeline where KF%6==0 (QKVU, P, out):
//   - A triple-buffered, issued at TOP of iter kf for kf+2 into (kf+2)%3 (the
//     buffer freed at kf-1) -> A lead ~2 iterations (~820 cyc).
//   - B stays 2-buf issued after MFMAS (in-order vmcnt keeps B drain position).
//   - regs: 48(A)+32(B)+64(acc)+~12 addr = ~156 < 170 -> keeps 3 waves/SIMD.
// AV (KF=64, 64%6!=0 would force dynamic %3 indexing -> scratch) keeps R11 loop.

typedef __attribute__((ext_vector_type(8))) short short8;
typedef __attribute__((ext_vector_type(4))) float floatx4;

constexpr int HD = 768;
constexpr int TT = 2048;
constexpr long WElem = 589824;     // 768*768
constexpr long QKpb  = 1572864;    // 2048*768 shorts per batch
constexpr long Ppb   = 4194304;    // 2048*2048 shorts per batch

__device__ __forceinline__ short f2bf(float x) {
  unsigned u = __builtin_bit_cast(unsigned, x);
  u = u + 0x7fffu + ((u >> 16) & 1u);   // RNE
  return (short)(u >> 16);
}
__device__ __forceinline__ float bf2f(short s) {
  unsigned u = ((unsigned)(unsigned short)s) << 16;
  return __builtin_bit_cast(float, u);
}

// kf-major packed offset (in shorts) of element (i, c) of a row-major [R x C]
// matrix, KF = C/32. Layout: [strip = i>>6][kf = c>>5][frag mi = (i>>4)&3][512].
// Within-frag: lane = ((c&31)>>3)*16 + (i&15), elem = c&7.
__device__ __forceinline__ long pL(int i, int c, int KF) {
  return (((long)(i >> 6) * KF + (c >> 5)) * 4 + ((i >> 4) & 3)) * 512 +
         ((c & 31) >> 3) * 128 + (i & 15) * 8 + (c & 7);
}

// ---------------- LayerNorm + bf16 cast, writes x in packed-frag order ------------
__global__ __launch_bounds__(256) void ln_kernel(
    const float* __restrict__ x, const float* __restrict__ g,
    const float* __restrict__ b, short* __restrict__ out) {
  int row = blockIdx.x;
  const float* xr = x + (long)row * HD;
  int t = threadIdx.x;
  float v0 = xr[t], v1 = xr[t + 256], v2 = xr[t + 512];
  float s = v0 + v1 + v2;
  float ss = v0 * v0 + v1 * v1 + v2 * v2;
#pragma unroll
  for (int o = 32; o > 0; o >>= 1) {
    s += __shfl_down(s, o);
    ss += __shfl_down(ss, o);
  }
  __shared__ float red[8];
  int wid = t >> 6;
  if ((t & 63) == 0) { red[wid] = s; red[4 + wid] = ss; }
  __syncthreads();
  float S = red[0] + red[1] + red[2] + red[3];
  float SS = red[4] + red[5] + red[6] + red[7];
  float mean = S * (1.0f / HD);
  float var = SS * (1.0f / HD) - mean * mean;
  float rstd = rsqrtf(var + 1e-5f);
  out[pL(row, t, 24)]       = f2bf((v0 - mean) * rstd * g[t]       + b[t]);
  out[pL(row, t + 256, 24)] = f2bf((v1 - mean) * rstd * g[t + 256] + b[t + 256]);
  out[pL(row, t + 512, 24)] = f2bf((v2 - mean) * rstd * g[t + 512] + b[t + 512]);
}

// ---------------- fp32 -> packed bf16 weights + bias concat ------------------------
__global__ __launch_bounds__(256) void convert_kernel(
    const float* __restrict__ wu, const float* __restrict__ wq,
    const float* __restrict__ wk, const float* __restrict__ wv,
    const float* __restrict__ wo,
    const float* __restrict__ bu, const float* __restrict__ bq,
    const float* __restrict__ bk, const float* __restrict__ bv,
    short* __restrict__ Wb, float* __restrict__ bcat) {
  long i = (long)blockIdx.x * 256 + threadIdx.x;
  if (i < 5 * WElem) {
    int which = (int)(i / WElem);
    long off = i - (long)which * WElem;
    const float* src = which == 0 ? wu : which == 1 ? wq : which == 2 ? wk
                     : which == 3 ? wv : wo;
    int n = (int)(off / HD), k = (int)(off - (long)n * HD);
    Wb[(long)which * WElem + pL(n, k, 24)] = f2bf(src[off]);
  }
  if (i < 4 * HD) {
    int which = (int)(i / HD);
    int off = (int)(i - which * HD);
    const float* src = which == 0 ? bu : which == 1 ? bq : which == 2 ? bk : bv;
    bcat[i] = src[off];
  }
}

// ---------------- barrier-free streaming GEMM ---------------------------------------
// 4 waves arranged WM x WN (WM = 4/WN); wave tile 64 x (TN*16).
// 1-D grid, XCD-aware decode (flat%8 = XCD owns a contiguous by-stripe).
// kf-major packed operands; ni-outer MFMA; DEEP: A 3-buf early-issue (KF%6==0).
template <int EPI, int KF, int GZ, int TN, int WN, int GY, bool DEEP>
__global__ __launch_bounds__(256, 3) void wgemm(
    const short* __restrict__ Ag, const short* __restrict__ Bg,
    long sAz, long sBz,
    short* __restrict__ o0, short* __restrict__ o1,
    short* __restrict__ o2, short* __restrict__ o3,
    float* __restrict__ outf, const float* __restrict__ bias,
    const short* __restrict__ umul) {
  constexpr int TM = 4;
  constexpr int WM = 4 / WN;
  constexpr int GYX = (GZ == 1) ? GY / 8 : GY / 2;   // by-range per XCD
  int f = blockIdx.x;
  int xcd = f & 7, i = f >> 3;
  int bx = i / GYX, byo = i % GYX;
  int z, by;
  if constexpr (GZ == 1) { z = 0;        by = xcd * GYX + byo; }
  else                   { z = xcd >> 1; by = (xcd & 1) * GYX + byo; }

  int t = threadIdx.x, w = t >> 6, lane = t & 63;
  int qd = lane >> 4, l15 = lane & 15;
  int wm = w / WN, wn = w % WN;
  int mf0 = (by * WM + wm) * TM;               // frag-row index (strip-aligned)
  int nf0 = (bx * WN + wn) * TN;               // frag-col index
  const short* aB = Ag + (long)z * sAz + (long)(mf0 >> 2) * KF * 2048 + lane * 8;
  const short* bB = Bg + (long)z * sBz + (long)(nf0 >> 2) * KF * 2048 +
                    (nf0 & 3) * 512 + lane * 8;

  floatx4 acc[TM][TN] = {};

#define LDA_(pa, kf)                                                        \
  { _Pragma("unroll") for (int mi = 0; mi < TM; mi++)                       \
        a[pa][mi] = *(const short8*)(aB + ((kf) * 4 + mi) * 512); }
#define LDB_(pb, kf)                                                        \
  { _Pragma("unroll") for (int ni = 0; ni < TN; ni++)                       \
        b[pb][ni] = *(const short8*)(bB + ((kf) * 4 + ni) * 512); }
  // ni-outer: group ni needs a0..a3 + b[ni] -> progressive vmcnt
#define MFMAS_(pa, pb)                                                      \
  { _Pragma("unroll") for (int ni = 0; ni < TN; ni++)                       \
        _Pragma("unroll") for (int mi = 0; mi < TM; mi++)                   \
            acc[mi][ni] = __builtin_amdgcn_mfma_f32_16x16x32_bf16(          \
                a[pa][mi], b[pb][ni], acc[mi][ni], 0, 0, 0); }

  if constexpr (DEEP) {
    short8 a[3][TM], b[2][TN];
    LDA_(0, 0) LDB_(0, 0) LDA_(1, 1) LDB_(1, 1)
#pragma unroll 6
    for (int kf = 0; kf < KF; ++kf) {
      if (kf + 2 < KF) LDA_((kf + 2) % 3, kf + 2)   // buffer freed at kf-1
      MFMAS_(kf % 3, kf & 1)
      if (kf + 2 < KF) LDB_(kf & 1, kf + 2)         // buffer consumed just now
    }
  } else {
    short8 a[2][TM], b[2][TN];
    LDA_(0, 0) LDB_(0, 0) LDA_(1, 1) LDB_(1, 1)
#pragma unroll 2
    for (int kf = 0; kf < KF; ++kf) {
      MFMAS_(kf & 1, kf & 1)
      if (kf + 2 < KF) { LDA_(kf & 1, kf + 2) LDB_(kf & 1, kf + 2) }
    }
  }
#undef LDA_
#undef LDB_
#undef MFMAS_

  // epilogue: lane holds D[row = qd*4+r][col = l15] per 16x16 frag
#pragma unroll
  for (int mi = 0; mi < TM; mi++)
#pragma unroll
    for (int ni = 0; ni < TN; ni++) {
      int mB = (mf0 + mi) * 16 + qd * 4;
      int col = (nf0 + ni) * 16 + l15;
#pragma unroll
      for (int r = 0; r < 4; r++) {
        int m = mB + r;
        float v = acc[mi][ni][r];
        if constexpr (EPI == 0) {
          v += bias[col];
          v = v / (1.0f + __expf(-v));  // silu
          short sv = f2bf(v);
          int which = col / HD;
          int d = col - which * HD;
          int batch = m >> 11, ii = m & (TT - 1);
          if (which == 0)      o0[(long)m * HD + d] = sv;                      // U row-major
          else if (which == 1) o1[(long)batch * QKpb + pL(ii, d, 24)] = sv;    // Q pack
          else if (which == 2) o2[(long)batch * QKpb + pL(ii, d, 24)] = sv;    // K pack
          else                 o3[(long)batch * QKpb + pL(d, ii, 64)] = sv;    // Vt pack
        } else if constexpr (EPI == 1) {
          v *= 0.022097086912079608f;   // 1/sqrt(2048)
          v = fmaxf(v, 0.0f);
          v = v * v;
          o0[(long)z * Ppb + pL(m, col, 64)] = f2bf(v);                        // P pack
        } else if constexpr (EPI == 2) {
          long gm = (long)z * TT + m;
          float um = bf2f(umul[gm * HD + col]);
          o0[pL((int)gm, col, 24)] = f2bf(v * um);                             // G pack
        } else {
          outf[(long)m * HD + col] = v + bias[col];
        }
      }
    }
}

extern "C" void kernel_launch(void* const* d_in, const int* in_sizes, int n_in,
                              void* d_out, int out_size, void* d_ws, size_t ws_size,
                              hipStream_t stream) {
  (void)in_sizes; (void)n_in; (void)out_size; (void)ws_size;
  const float* hid = (const float*)d_in[0];
  const float* lng = (const float*)d_in[1];
  const float* lnb = (const float*)d_in[2];
  const float* Wu  = (const float*)d_in[3];
  const float* bu  = (const float*)d_in[4];
  const float* Wq  = (const float*)d_in[5];
  const float* bq  = (const float*)d_in[6];
  const float* Wk  = (const float*)d_in[7];
  const float* bk  = (const float*)d_in[8];
  const float* Wv  = (const float*)d_in[9];
  const float* bv  = (const float*)d_in[10];
  const float* Wo  = (const float*)d_in[11];
  const float* bo  = (const float*)d_in[12];

  // workspace layout (bytes); packed buffers
  char* ws = (char*)d_ws;
  short* Wb   = (short*)(ws);                 // 5*589824 bf16 = 5,898,240 B (packed)
  float* bcat = (float*)(ws + 5898240);       // 3072 fp32     =    12,288 B
  short* xbf  = (short*)(ws + 5910528);       // x pack, 12,582,912 B
  short* Ub   = (short*)(ws + 18493440);      // U row-major, 12,582,912 B
  short* Qb   = (short*)(ws + 31076352);      // Q pack, 12,582,912 B
  short* Kb   = (short*)(ws + 43659264);      // K pack, 12,582,912 B
  short* Vt   = (short*)(ws + 56242176);      // Vt pack, 12,582,912 B
  short* Pb   = (short*)(ws + 68825088);      // P pack, 33,554,432 B
  short* Gb   = (short*)(ws + 102379520);     // G pack, 12,582,912 B (total ~115 MB)

  convert_kernel<<<11520, 256, 0, stream>>>(Wu, Wq, Wk, Wv, Wo, bu, bq, bk, bv, Wb, bcat);
  ln_kernel<<<8192, 256, 0, stream>>>(hid, lng, lnb, xbf);

  // U,Q,K,V = silu(x @ Wcat^T + bcat): block 128x128 (2x2), GY=64, GX=24, DEEP
  wgemm<0, 24, 1, 4, 2, 64, true><<<1536, 256, 0, stream>>>(
      xbf, Wb, 0, 0, Ub, Qb, Kb, Vt, nullptr, bcat, nullptr);

  // P = relu(QK^T/sqrt(T))^2 per batch: block 128x128 (2x2), GY=16, GX=16, GZ=4, DEEP
  wgemm<1, 24, 4, 4, 2, 16, true><<<1024, 256, 0, stream>>>(
      Qb, Kb, QKpb, QKpb, Pb, nullptr, nullptr, nullptr, nullptr, nullptr, nullptr);

  // G = (P @ V) * U per batch: block 128x64 (2x2, TN=2), GY=16, GX=12, GZ=4 (KF=64)
  wgemm<2, 64, 4, 2, 2, 16, false><<<768, 256, 0, stream>>>(
      Pb, Vt, Ppb, QKpb, Gb, nullptr, nullptr, nullptr, nullptr, nullptr, Ub);

  // out = G @ Wo^T + bo: block 128x64 (2x2, TN=2), GY=64, GX=12, GZ=1, fp32, DEEP
  wgemm<3, 24, 1, 2, 2, 64, true><<<768, 256, 0, stream>>>(
      Gb, Wb + 4 * WElem, 0, 0, nullptr, nullptr, nullptr, nullptr,
      (float*)d_out, bo, nullptr);
}

// Round 13
// 280.715 us; speedup vs baseline: 1.0596x; 1.0596x over previous
//
#include <hip/hip_runtime.h>
#include <math.h>

// GAU attention: LN -> silu(x@W^T+b) x4 -> P=relu^2(QK^T/sqrt(T)) -> AV=P@V -> (U*AV)@Wo^T+bo
// R13: R11 base (kf-major packed register streaming, 2x2 waves, ni-outer, XCD remap,
// dist-2 ping-pong). For the TN=4 kernels (QKVU, P): B single-buffered with
// STAGGERED per-group refill (b[ni] refilled for kf+1 right after its last MFMA
// reader in the ni-outer order -> same ~1-iter flight as dbuf, 16 fewer VGPRs)
// -> ~120 total regs -> __launch_bounds__(256,4) -> 4 blocks/CU (was 3).
// R8/R12 lesson: >2A+2B live buffers spills — this SHRINKS buffers instead.

typedef __attribute__((ext_vector_type(8))) short short8;
typedef __attribute__((ext_vector_type(4))) float floatx4;

constexpr int HD = 768;
constexpr int TT = 2048;
constexpr long WElem = 589824;     // 768*768
constexpr long QKpb  = 1572864;    // 2048*768 shorts per batch
constexpr long Ppb   = 4194304;    // 2048*2048 shorts per batch

__device__ __forceinline__ short f2bf(float x) {
  unsigned u = __builtin_bit_cast(unsigned, x);
  u = u + 0x7fffu + ((u >> 16) & 1u);   // RNE
  return (short)(u >> 16);
}
__device__ __forceinline__ float bf2f(short s) {
  unsigned u = ((unsigned)(unsigned short)s) << 16;
  return __builtin_bit_cast(float, u);
}

// kf-major packed offset (in shorts) of element (i, c) of a row-major [R x C]
// matrix, KF = C/32. Layout: [strip = i>>6][kf = c>>5][frag mi = (i>>4)&3][512].
// Within-frag: lane = ((c&31)>>3)*16 + (i&15), elem = c&7.
__device__ __forceinline__ long pL(int i, int c, int KF) {
  return (((long)(i >> 6) * KF + (c >> 5)) * 4 + ((i >> 4) & 3)) * 512 +
         ((c & 31) >> 3) * 128 + (i & 15) * 8 + (c & 7);
}

// ---------------- LayerNorm + bf16 cast, writes x in packed-frag order ------------
__global__ __launch_bounds__(256) void ln_kernel(
    const float* __restrict__ x, const float* __restrict__ g,
    const float* __restrict__ b, short* __restrict__ out) {
  int row = blockIdx.x;
  const float* xr = x + (long)row * HD;
  int t = threadIdx.x;
  float v0 = xr[t], v1 = xr[t + 256], v2 = xr[t + 512];
  float s = v0 + v1 + v2;
  float ss = v0 * v0 + v1 * v1 + v2 * v2;
#pragma unroll
  for (int o = 32; o > 0; o >>= 1) {
    s += __shfl_down(s, o);
    ss += __shfl_down(ss, o);
  }
  __shared__ float red[8];
  int wid = t >> 6;
  if ((t & 63) == 0) { red[wid] = s; red[4 + wid] = ss; }
  __syncthreads();
  float S = red[0] + red[1] + red[2] + red[3];
  float SS = red[4] + red[5] + red[6] + red[7];
  float mean = S * (1.0f / HD);
  float var = SS * (1.0f / HD) - mean * mean;
  float rstd = rsqrtf(var + 1e-5f);
  out[pL(row, t, 24)]       = f2bf((v0 - mean) * rstd * g[t]       + b[t]);
  out[pL(row, t + 256, 24)] = f2bf((v1 - mean) * rstd * g[t + 256] + b[t + 256]);
  out[pL(row, t + 512, 24)] = f2bf((v2 - mean) * rstd * g[t + 512] + b[t + 512]);
}

// ---------------- fp32 -> packed bf16 weights + bias concat ------------------------
__global__ __launch_bounds__(256) void convert_kernel(
    const float* __restrict__ wu, const float* __restrict__ wq,
    const float* __restrict__ wk, const float* __restrict__ wv,
    const float* __restrict__ wo,
    const float* __restrict__ bu, const float* __restrict__ bq,
    const float* __restrict__ bk, const float* __restrict__ bv,
    short* __restrict__ Wb, float* __restrict__ bcat) {
  long i = (long)blockIdx.x * 256 + threadIdx.x;
  if (i < 5 * WElem) {
    int which = (int)(i / WElem);
    long off = i - (long)which * WElem;
    const float* src = which == 0 ? wu : which == 1 ? wq : which == 2 ? wk
                     : which == 3 ? wv : wo;
    int n = (int)(off / HD), k = (int)(off - (long)n * HD);
    Wb[(long)which * WElem + pL(n, k, 24)] = f2bf(src[off]);
  }
  if (i < 4 * HD) {
    int which = (int)(i / HD);
    int off = (int)(i - which * HD);
    const float* src = which == 0 ? bu : which == 1 ? bq : which == 2 ? bk : bv;
    bcat[i] = src[off];
  }
}

// ---------------- barrier-free streaming GEMM ---------------------------------------
// 4 waves arranged WM x WN (WM = 4/WN); wave tile 64 x (TN*16).
// 1-D grid, XCD-aware decode (flat%8 = XCD owns a contiguous by-stripe).
// kf-major packed operands; ni-outer MFMA.
// B1: single B buffer, staggered per-group refill + launch_bounds(256,4).
template <int EPI, int KF, int GZ, int TN, int WN, int GY, bool B1, int MW>
__global__ __launch_bounds__(256, MW) void wgemm(
    const short* __restrict__ Ag, const short* __restrict__ Bg,
    long sAz, long sBz,
    short* __restrict__ o0, short* __restrict__ o1,
    short* __restrict__ o2, short* __restrict__ o3,
    float* __restrict__ outf, const float* __restrict__ bias,
    const short* __restrict__ umul) {
  constexpr int TM = 4;
  constexpr int WM = 4 / WN;
  constexpr int GYX = (GZ == 1) ? GY / 8 : GY / 2;   // by-range per XCD
  int f = blockIdx.x;
  int xcd = f & 7, i = f >> 3;
  int bx = i / GYX, byo = i % GYX;
  int z, by;
  if constexpr (GZ == 1) { z = 0;        by = xcd * GYX + byo; }
  else                   { z = xcd >> 1; by = (xcd & 1) * GYX + byo; }

  int t = threadIdx.x, w = t >> 6, lane = t & 63;
  int qd = lane >> 4, l15 = lane & 15;
  int wm = w / WN, wn = w % WN;
  int mf0 = (by * WM + wm) * TM;               // frag-row index (strip-aligned)
  int nf0 = (bx * WN + wn) * TN;               // frag-col index
  const short* aB = Ag + (long)z * sAz + (long)(mf0 >> 2) * KF * 2048 + lane * 8;
  const short* bB = Bg + (long)z * sBz + (long)(nf0 >> 2) * KF * 2048 +
                    (nf0 & 3) * 512 + lane * 8;

  floatx4 acc[TM][TN] = {};

#define LDA_(pa, kf)                                                        \
  { _Pragma("unroll") for (int mi = 0; mi < TM; mi++)                       \
        a[pa][mi] = *(const short8*)(aB + ((kf) * 4 + mi) * 512); }

  if constexpr (B1) {
    short8 a[2][TM], b[TN];
    LDA_(0, 0)
#pragma unroll
    for (int ni = 0; ni < TN; ni++)
      b[ni] = *(const short8*)(bB + ni * 512);
    LDA_(1, 1)
#pragma unroll 2
    for (int kf = 0; kf < KF; ++kf) {
#pragma unroll
      for (int ni = 0; ni < TN; ni++) {
#pragma unroll
        for (int mi = 0; mi < TM; mi++)
          acc[mi][ni] = __builtin_amdgcn_mfma_f32_16x16x32_bf16(
              a[kf & 1][mi], b[ni], acc[mi][ni], 0, 0, 0);
        if (kf + 1 < KF)   // last reader of b[ni] was above -> refill for kf+1
          b[ni] = *(const short8*)(bB + ((kf + 1) * 4 + ni) * 512);
      }
      if (kf + 2 < KF) LDA_(kf & 1, kf + 2)
    }
  } else {
    short8 a[2][TM], b[2][TN];
    LDA_(0, 0)
#pragma unroll
    for (int ni = 0; ni < TN; ni++) b[0][ni] = *(const short8*)(bB + ni * 512);
    LDA_(1, 1)
#pragma unroll
    for (int ni = 0; ni < TN; ni++) b[1][ni] = *(const short8*)(bB + (4 + ni) * 512);
#pragma unroll 2
    for (int kf = 0; kf < KF; ++kf) {
#pragma unroll
      for (int ni = 0; ni < TN; ni++)
#pragma unroll
        for (int mi = 0; mi < TM; mi++)
          acc[mi][ni] = __builtin_amdgcn_mfma_f32_16x16x32_bf16(
              a[kf & 1][mi], b[kf & 1][ni], acc[mi][ni], 0, 0, 0);
      if (kf + 2 < KF) {
        LDA_(kf & 1, kf + 2)
#pragma unroll
        for (int ni = 0; ni < TN; ni++)
          b[kf & 1][ni] = *(const short8*)(bB + ((kf + 2) * 4 + ni) * 512);
      }
    }
  }
#undef LDA_

  // epilogue: lane holds D[row = qd*4+r][col = l15] per 16x16 frag
#pragma unroll
  for (int mi = 0; mi < TM; mi++)
#pragma unroll
    for (int ni = 0; ni < TN; ni++) {
      int mB = (mf0 + mi) * 16 + qd * 4;
      int col = (nf0 + ni) * 16 + l15;
#pragma unroll
      for (int r = 0; r < 4; r++) {
        int m = mB + r;
        float v = acc[mi][ni][r];
        if constexpr (EPI == 0) {
          v += bias[col];
          v = v / (1.0f + __expf(-v));  // silu
          short sv = f2bf(v);
          int which = col / HD;
          int d = col - which * HD;
          int batch = m >> 11, ii = m & (TT - 1);
          if (which == 0)      o0[(long)m * HD + d] = sv;                      // U row-major
          else if (which == 1) o1[(long)batch * QKpb + pL(ii, d, 24)] = sv;    // Q pack
          else if (which == 2) o2[(long)batch * QKpb + pL(ii, d, 24)] = sv;    // K pack
          else                 o3[(long)batch * QKpb + pL(d, ii, 64)] = sv;    // Vt pack
        } else if constexpr (EPI == 1) {
          v *= 0.022097086912079608f;   // 1/sqrt(2048)
          v = fmaxf(v, 0.0f);
          v = v * v;
          o0[(long)z * Ppb + pL(m, col, 64)] = f2bf(v);                        // P pack
        } else if constexpr (EPI == 2) {
          long gm = (long)z * TT + m;
          float um = bf2f(umul[gm * HD + col]);
          o0[pL((int)gm, col, 24)] = f2bf(v * um);                             // G pack
        } else {
          outf[(long)m * HD + col] = v + bias[col];
        }
      }
    }
}

extern "C" void kernel_launch(void* const* d_in, const int* in_sizes, int n_in,
                              void* d_out, int out_size, void* d_ws, size_t ws_size,
                              hipStream_t stream) {
  (void)in_sizes; (void)n_in; (void)out_size; (void)ws_size;
  const float* hid = (const float*)d_in[0];
  const float* lng = (const float*)d_in[1];
  const float* lnb = (const float*)d_in[2];
  const float* Wu  = (const float*)d_in[3];
  const float* bu  = (const float*)d_in[4];
  const float* Wq  = (const float*)d_in[5];
  const float* bq  = (const float*)d_in[6];
  const float* Wk  = (const float*)d_in[7];
  const float* bk  = (const float*)d_in[8];
  const float* Wv  = (const float*)d_in[9];
  const float* bv  = (const float*)d_in[10];
  const float* Wo  = (const float*)d_in[11];
  const float* bo  = (const float*)d_in[12];

  // workspace layout (bytes); packed buffers
  char* ws = (char*)d_ws;
  short* Wb   = (short*)(ws);                 // 5*589824 bf16 = 5,898,240 B (packed)
  float* bcat = (float*)(ws + 5898240);       // 3072 fp32     =    12,288 B
  short* xbf  = (short*)(ws + 5910528);       // x pack, 12,582,912 B
  short* Ub   = (short*)(ws + 18493440);      // U row-major, 12,582,912 B
  short* Qb   = (short*)(ws + 31076352);      // Q pack, 12,582,912 B
  short* Kb   = (short*)(ws + 43659264);      // K pack, 12,582,912 B
  short* Vt   = (short*)(ws + 56242176);      // Vt pack, 12,582,912 B
  short* Pb   = (short*)(ws + 68825088);      // P pack, 33,554,432 B
  short* Gb   = (short*)(ws + 102379520);     // G pack, 12,582,912 B (total ~115 MB)

  convert_kernel<<<11520, 256, 0, stream>>>(Wu, Wq, Wk, Wv, Wo, bu, bq, bk, bv, Wb, bcat);
  ln_kernel<<<8192, 256, 0, stream>>>(hid, lng, lnb, xbf);

  // U,Q,K,V = silu(x @ Wcat^T + bcat): block 128x128 (2x2), GY=64, GX=24, B1+MW4
  wgemm<0, 24, 1, 4, 2, 64, true, 4><<<1536, 256, 0, stream>>>(
      xbf, Wb, 0, 0, Ub, Qb, Kb, Vt, nullptr, bcat, nullptr);

  // P = relu(QK^T/sqrt(T))^2 per batch: block 128x128 (2x2), GY=16, GX=16, GZ=4, B1+MW4
  wgemm<1, 24, 4, 4, 2, 16, true, 4><<<1024, 256, 0, stream>>>(
      Qb, Kb, QKpb, QKpb, Pb, nullptr, nullptr, nullptr, nullptr, nullptr, nullptr);

  // G = (P @ V) * U per batch: block 128x64 (2x2, TN=2), GY=16, GX=12, GZ=4 (R11 path)
  wgemm<2, 64, 4, 2, 2, 16, false, 3><<<768, 256, 0, stream>>>(
      Pb, Vt, Ppb, QKpb, Gb, nullptr, nullptr, nullptr, nullptr, nullptr, Ub);

  // out = G @ Wo^T + bo: block 128x64 (2x2, TN=2), GY=64, GX=12, GZ=1, fp32 (R11 path)
  wgemm<3, 24, 1, 2, 2, 64, false, 3><<<768, 256, 0, stream>>>(
      Gb, Wb + 4 * WElem, 0, 0, nullptr, nullptr, nullptr, nullptr,
      (float*)d_out, bo, nullptr);
}

// Round 14
// 274.448 us; speedup vs baseline: 1.0838x; 1.0228x over previous
//
#include <hip/hip_runtime.h>
#include <math.h>

// GAU attention: LN -> silu(x@W^T+b) x4 -> P=relu^2(QK^T/sqrt(T)) -> AV=P@V -> (U*AV)@Wo^T+bo
// R14: exact R11 structure (kf-major packed register streaming, 2x2 waves, TN=4 for
// QKVU/P, TN=2 for AV/out, dist-2 ping-pong A+B, ni-outer, XCD remap, 3 waves/SIMD)
// + explicit prefetch-pointer addressing: one aP/bP pointer bumped 4KB per iter,
// all 8 loads use immediate offsets (0..3KB) -> ~4 VALU/iter instead of ~16
// (R11 VALUBusy 37% ~= MfMA issue traffic; address materialization was stealing
// issue slots). Depth ledger: <2 buffers worse (R13), >2 spills (R8/R12), =2 best.

typedef __attribute__((ext_vector_type(8))) short short8;
typedef __attribute__((ext_vector_type(4))) float floatx4;

constexpr int HD = 768;
constexpr int TT = 2048;
constexpr long WElem = 589824;     // 768*768
constexpr long QKpb  = 1572864;    // 2048*768 shorts per batch
constexpr long Ppb   = 4194304;    // 2048*2048 shorts per batch

__device__ __forceinline__ short f2bf(float x) {
  unsigned u = __builtin_bit_cast(unsigned, x);
  u = u + 0x7fffu + ((u >> 16) & 1u);   // RNE
  return (short)(u >> 16);
}
__device__ __forceinline__ float bf2f(short s) {
  unsigned u = ((unsigned)(unsigned short)s) << 16;
  return __builtin_bit_cast(float, u);
}

// kf-major packed offset (in shorts) of element (i, c) of a row-major [R x C]
// matrix, KF = C/32. Layout: [strip = i>>6][kf = c>>5][frag mi = (i>>4)&3][512].
// Within-frag: lane = ((c&31)>>3)*16 + (i&15), elem = c&7.
__device__ __forceinline__ long pL(int i, int c, int KF) {
  return (((long)(i >> 6) * KF + (c >> 5)) * 4 + ((i >> 4) & 3)) * 512 +
         ((c & 31) >> 3) * 128 + (i & 15) * 8 + (c & 7);
}

// ---------------- LayerNorm + bf16 cast, writes x in packed-frag order ------------
__global__ __launch_bounds__(256) void ln_kernel(
    const float* __restrict__ x, const float* __restrict__ g,
    const float* __restrict__ b, short* __restrict__ out) {
  int row = blockIdx.x;
  const float* xr = x + (long)row * HD;
  int t = threadIdx.x;
  float v0 = xr[t], v1 = xr[t + 256], v2 = xr[t + 512];
  float s = v0 + v1 + v2;
  float ss = v0 * v0 + v1 * v1 + v2 * v2;
#pragma unroll
  for (int o = 32; o > 0; o >>= 1) {
    s += __shfl_down(s, o);
    ss += __shfl_down(ss, o);
  }
  __shared__ float red[8];
  int wid = t >> 6;
  if ((t & 63) == 0) { red[wid] = s; red[4 + wid] = ss; }
  __syncthreads();
  float S = red[0] + red[1] + red[2] + red[3];
  float SS = red[4] + red[5] + red[6] + red[7];
  float mean = S * (1.0f / HD);
  float var = SS * (1.0f / HD) - mean * mean;
  float rstd = rsqrtf(var + 1e-5f);
  out[pL(row, t, 24)]       = f2bf((v0 - mean) * rstd * g[t]       + b[t]);
  out[pL(row, t + 256, 24)] = f2bf((v1 - mean) * rstd * g[t + 256] + b[t + 256]);
  out[pL(row, t + 512, 24)] = f2bf((v2 - mean) * rstd * g[t + 512] + b[t + 512]);
}

// ---------------- fp32 -> packed bf16 weights + bias concat ------------------------
__global__ __launch_bounds__(256) void convert_kernel(
    const float* __restrict__ wu, const float* __restrict__ wq,
    const float* __restrict__ wk, const float* __restrict__ wv,
    const float* __restrict__ wo,
    const float* __restrict__ bu, const float* __restrict__ bq,
    const float* __restrict__ bk, const float* __restrict__ bv,
    short* __restrict__ Wb, float* __restrict__ bcat) {
  long i = (long)blockIdx.x * 256 + threadIdx.x;
  if (i < 5 * WElem) {
    int which = (int)(i / WElem);
    long off = i - (long)which * WElem;
    const float* src = which == 0 ? wu : which == 1 ? wq : which == 2 ? wk
                     : which == 3 ? wv : wo;
    int n = (int)(off / HD), k = (int)(off - (long)n * HD);
    Wb[(long)which * WElem + pL(n, k, 24)] = f2bf(src[off]);
  }
  if (i < 4 * HD) {
    int which = (int)(i / HD);
    int off = (int)(i - which * HD);
    const float* src = which == 0 ? bu : which == 1 ? bq : which == 2 ? bk : bv;
    bcat[i] = src[off];
  }
}

// ---------------- barrier-free streaming GEMM ---------------------------------------
// 4 waves arranged WM x WN (WM = 4/WN); wave tile 64 x (TN*16).
// 1-D grid, XCD-aware decode (flat%8 = XCD owns a contiguous by-stripe).
// kf-major packed operands; ni-outer MFMA; dist-2 ping-pong with prefetch pointers.
template <int EPI, int KF, int GZ, int TN, int WN, int GY>
__global__ __launch_bounds__(256, 3) void wgemm(
    const short* __restrict__ Ag, const short* __restrict__ Bg,
    long sAz, long sBz,
    short* __restrict__ o0, short* __restrict__ o1,
    short* __restrict__ o2, short* __restrict__ o3,
    float* __restrict__ outf, const float* __restrict__ bias,
    const short* __restrict__ umul) {
  constexpr int TM = 4;
  constexpr int WM = 4 / WN;
  constexpr int GYX = (GZ == 1) ? GY / 8 : GY / 2;   // by-range per XCD
  int f = blockIdx.x;
  int xcd = f & 7, i = f >> 3;
  int bx = i / GYX, byo = i % GYX;
  int z, by;
  if constexpr (GZ == 1) { z = 0;        by = xcd * GYX + byo; }
  else                   { z = xcd >> 1; by = (xcd & 1) * GYX + byo; }

  int t = threadIdx.x, w = t >> 6, lane = t & 63;
  int qd = lane >> 4, l15 = lane & 15;
  int wm = w / WN, wn = w % WN;
  int mf0 = (by * WM + wm) * TM;               // frag-row index (strip-aligned)
  int nf0 = (bx * WN + wn) * TN;               // frag-col index
  // prefetch pointers: advance 2048 shorts (4 KB = one kf of 4 frags) per iter;
  // all loads are immediate-offset (mi*1024 B <= 3072 <= 4095) off these.
  const short* aP = Ag + (long)z * sAz + (long)(mf0 >> 2) * KF * 2048 + lane * 8;
  const short* bP = Bg + (long)z * sBz + (long)(nf0 >> 2) * KF * 2048 +
                    (nf0 & 3) * 512 + lane * 8;

  floatx4 acc[TM][TN] = {};
  short8 a[2][TM], b[2][TN];

#define LDSTEP(p)                                                           \
  {                                                                         \
    _Pragma("unroll") for (int mi = 0; mi < TM; mi++)                       \
        a[p][mi] = *(const short8*)(aP + mi * 512);                         \
    _Pragma("unroll") for (int ni = 0; ni < TN; ni++)                       \
        b[p][ni] = *(const short8*)(bP + ni * 512);                         \
    aP += 2048; bP += 2048;                                                 \
  }
  // ni-outer: group ni needs a0..a3 + b[ni] -> progressive vmcnt
#define MFMAS(p)                                                            \
  {                                                                         \
    _Pragma("unroll") for (int ni = 0; ni < TN; ni++)                       \
        _Pragma("unroll") for (int mi = 0; mi < TM; mi++)                   \
            acc[mi][ni] = __builtin_amdgcn_mfma_f32_16x16x32_bf16(          \
                a[p][mi], b[p][ni], acc[mi][ni], 0, 0, 0);                  \
  }

  LDSTEP(0)
  LDSTEP(1)
#pragma unroll 2
  for (int kf = 0; kf < KF; ++kf) {
    MFMAS(kf & 1)
    if (kf + 2 < KF) LDSTEP(kf & 1)           // refill the buffer just consumed
  }
#undef LDSTEP
#undef MFMAS

  // epilogue: lane holds D[row = qd*4+r][col = l15] per 16x16 frag
#pragma unroll
  for (int mi = 0; mi < TM; mi++)
#pragma unroll
    for (int ni = 0; ni < TN; ni++) {
      int mB = (mf0 + mi) * 16 + qd * 4;
      int col = (nf0 + ni) * 16 + l15;
#pragma unroll
      for (int r = 0; r < 4; r++) {
        int m = mB + r;
        float v = acc[mi][ni][r];
        if constexpr (EPI == 0) {
          v += bias[col];
          v = v / (1.0f + __expf(-v));  // silu
          short sv = f2bf(v);
          int which = col / HD;
          int d = col - which * HD;
          int batch = m >> 11, ii = m & (TT - 1);
          if (which == 0)      o0[(long)m * HD + d] = sv;                      // U row-major
          else if (which == 1) o1[(long)batch * QKpb + pL(ii, d, 24)] = sv;    // Q pack
          else if (which == 2) o2[(long)batch * QKpb + pL(ii, d, 24)] = sv;    // K pack
          else                 o3[(long)batch * QKpb + pL(d, ii, 64)] = sv;    // Vt pack
        } else if constexpr (EPI == 1) {
          v *= 0.022097086912079608f;   // 1/sqrt(2048)
          v = fmaxf(v, 0.0f);
          v = v * v;
          o0[(long)z * Ppb + pL(m, col, 64)] = f2bf(v);                        // P pack
        } else if constexpr (EPI == 2) {
          long gm = (long)z * TT + m;
          float um = bf2f(umul[gm * HD + col]);
          o0[pL((int)gm, col, 24)] = f2bf(v * um);                             // G pack
        } else {
          outf[(long)m * HD + col] = v + bias[col];
        }
      }
    }
}

extern "C" void kernel_launch(void* const* d_in, const int* in_sizes, int n_in,
                              void* d_out, int out_size, void* d_ws, size_t ws_size,
                              hipStream_t stream) {
  (void)in_sizes; (void)n_in; (void)out_size; (void)ws_size;
  const float* hid = (const float*)d_in[0];
  const float* lng = (const float*)d_in[1];
  const float* lnb = (const float*)d_in[2];
  const float* Wu  = (const float*)d_in[3];
  const float* bu  = (const float*)d_in[4];
  const float* Wq  = (const float*)d_in[5];
  const float* bq  = (const float*)d_in[6];
  const float* Wk  = (const float*)d_in[7];
  const float* bk  = (const float*)d_in[8];
  const float* Wv  = (const float*)d_in[9];
  const float* bv  = (const float*)d_in[10];
  const float* Wo  = (const float*)d_in[11];
  const float* bo  = (const float*)d_in[12];

  // workspace layout (bytes); packed buffers
  char* ws = (char*)d_ws;
  short* Wb   = (short*)(ws);                 // 5*589824 bf16 = 5,898,240 B (packed)
  float* bcat = (float*)(ws + 5898240);       // 3072 fp32     =    12,288 B
  short* xbf  = (short*)(ws + 5910528);       // x pack, 12,582,912 B
  short* Ub   = (short*)(ws + 18493440);      // U row-major, 12,582,912 B
  short* Qb   = (short*)(ws + 31076352);      // Q pack, 12,582,912 B
  short* Kb   = (short*)(ws + 43659264);      // K pack, 12,582,912 B
  short* Vt   = (short*)(ws + 56242176);      // Vt pack, 12,582,912 B
  short* Pb   = (short*)(ws + 68825088);      // P pack, 33,554,432 B
  short* Gb   = (short*)(ws + 102379520);     // G pack, 12,582,912 B (total ~115 MB)

  convert_kernel<<<11520, 256, 0, stream>>>(Wu, Wq, Wk, Wv, Wo, bu, bq, bk, bv, Wb, bcat);
  ln_kernel<<<8192, 256, 0, stream>>>(hid, lng, lnb, xbf);

  // U,Q,K,V = silu(x @ Wcat^T + bcat): block 128x128 (2x2), GY=64, GX=24
  wgemm<0, 24, 1, 4, 2, 64><<<1536, 256, 0, stream>>>(
      xbf, Wb, 0, 0, Ub, Qb, Kb, Vt, nullptr, bcat, nullptr);

  // P = relu(QK^T/sqrt(T))^2 per batch: block 128x128 (2x2), GY=16, GX=16, GZ=4
  wgemm<1, 24, 4, 4, 2, 16><<<1024, 256, 0, stream>>>(
      Qb, Kb, QKpb, QKpb, Pb, nullptr, nullptr, nullptr, nullptr, nullptr, nullptr);

  // G = (P @ V) * U per batch: block 128x64 (2x2, TN=2), GY=16, GX=12, GZ=4
  wgemm<2, 64, 4, 2, 2, 16><<<768, 256, 0, stream>>>(
      Pb, Vt, Ppb, QKpb, Gb, nullptr, nullptr, nullptr, nullptr, nullptr, Ub);

  // out = G @ Wo^T + bo: block 128x64 (2x2, TN=2), GY=64, GX=12, GZ=1, fp32 out
  wgemm<3, 24, 1, 2, 2, 64><<<768, 256, 0, stream>>>(
      Gb, Wb + 4 * WElem, 0, 0, nullptr, nullptr, nullptr, nullptr,
      (float*)d_out, bo, nullptr);
}